// Round 5
// baseline (284.660 us; speedup 1.0000x reference)
//
#include <hip/hip_runtime.h>
#include <math.h>

#define EPSF 1e-8f

typedef _Float16 f16x8 __attribute__((ext_vector_type(8)));
typedef float f32x4 __attribute__((ext_vector_type(4)));

#define GLOAD_LDS16(g, l)                                                      \
  __builtin_amdgcn_global_load_lds(                                            \
      (const __attribute__((address_space(1))) unsigned int*)(g),              \
      (__attribute__((address_space(3))) unsigned int*)(l), 16, 0, 0)

__device__ __forceinline__ unsigned int ord_from_float(float f) {
  unsigned int u = __float_as_uint(f);
  return (u & 0x80000000u) ? ~u : (u | 0x80000000u);
}

__device__ __forceinline__ float float_from_ord(unsigned int o) {
  return (o & 0x80000000u) ? __uint_as_float(o & 0x7fffffffu)
                           : __uint_as_float(~o);
}

__device__ __forceinline__ unsigned long long shfl_xor_u64(unsigned long long x, int m) {
  int lo = __shfl_xor((int)(unsigned int)(x & 0xffffffffull), m, 64);
  int hi = __shfl_xor((int)(unsigned int)(x >> 32), m, 64);
  return ((unsigned long long)(unsigned int)hi << 32) | (unsigned int)lo;
}

// ---------------- fused prep kernels ----------------
// Acat row layout (K' = 3*DP): [ hi(log) | hi(log) | lo(log) ]; also writes s_in.
__global__ __launch_bounds__(64) void prep_A_kernel(
    const float* __restrict__ inp, _Float16* __restrict__ Acat,
    float* __restrict__ s_in, int N, int D, int DP) {
  int r = blockIdx.x;
  const size_t base = (size_t)r * (3 * DP);
  float s = 0.f;
  for (int d = threadIdx.x; d < DP; d += 64) {
    float lg = 0.f;
    if (r < N && d < D) {
      float x = inp[(size_t)r * D + d];
      s += x;
      lg = logf(x + EPSF);
    }
    _Float16 h = (_Float16)lg;
    _Float16 l = (_Float16)(lg - (float)h);
    Acat[base + d] = h;
    Acat[base + DP + d] = h;
    Acat[base + 2 * DP + d] = l;
  }
  #pragma unroll
  for (int m = 1; m < 64; m <<= 1) s += __shfl_xor(s, m, 64);
  if (threadIdx.x == 0 && r < N) s_in[r] = s;
}

// Bcat row layout: [ hi(tgt) | lo(tgt) | hi(tgt) ]; also writes Stirling sums.
__global__ __launch_bounds__(64) void prep_B_kernel(
    const float* __restrict__ tgt, _Float16* __restrict__ Bcat,
    float* __restrict__ s_st, int M, int D, int DP) {
  int r = blockIdx.x;
  const size_t base = (size_t)r * (3 * DP);
  float s = 0.f;
  for (int d = threadIdx.x; d < DP; d += 64) {
    float x = 0.f;
    if (r < M && d < D) {
      x = tgt[(size_t)r * D + d];
      if (x > 1.0f)
        s += x * logf(x) - x + 0.5f * logf(6.283185307179586f * x);
    }
    _Float16 h = (_Float16)x;
    _Float16 l = (_Float16)(x - (float)h);
    Bcat[base + d] = h;
    Bcat[base + DP + d] = l;
    Bcat[base + 2 * DP + d] = h;
  }
  #pragma unroll
  for (int m = 1; m < 64; m <<= 1) s += __shfl_xor(s, m, 64);
  if (threadIdx.x == 0 && r < M) s_st[r] = s;
}

// ---------------- MFMA pair-min kernel (2-phase double-buffered) ----------------
// cross[i][j] = Acat[i,:] . Bcat[j,:] over K'=3*DP (fp16 hi/lo split GEMM),
// global_load_lds staging with pre-swizzled source, fused min/argmin epilogue.
#define BMM 128
#define HBUF 4096  // halves per LDS buffer (128 rows x 32 halves)

__global__ __launch_bounds__(256) void mfma_pair_min_kernel(
    const _Float16* __restrict__ Acat, const _Float16* __restrict__ Bcat,
    const float* __restrict__ s_st, unsigned long long* __restrict__ packed,
    int N, int M, int DP3, int gx) {
  __shared__ __align__(16) _Float16 Ash[2 * HBUF];
  __shared__ __align__(16) _Float16 Bsh[2 * HBUF];
  const int t = threadIdx.x;
  const int lane = t & 63;
  const int wid = t >> 6;
  const int wr = wid >> 1, wc = wid & 1;

  // bijective XCD-chunk swizzle (m204)
  const int nwg = gridDim.x;
  const int xcd = blockIdx.x & 7;
  const int idx = blockIdx.x >> 3;
  const int qq = nwg >> 3, rr = nwg & 7;
  const int wg = (xcd < rr ? xcd * (qq + 1) : rr * (qq + 1) + (xcd - rr) * qq) + idx;
  const int row0 = (wg / gx) * BMM;
  const int col0 = (wg % gx) * BMM;

  f32x4 acc[4][4] = {};

  // Staging: wave `wid` owns rows [wid*32, wid*32+32) of A and B; 2 wave-loads
  // of 16 rows x 64B each. LDS dest linear; GLOBAL source slot pre-swizzled so
  // LDS(row,s) = global(row, s ^ ((row>>1)&3)) (round-3/4 verified, 0 conflicts).
  const int srow = lane >> 2;
  const int gs = (lane & 3) ^ ((lane >> 3) & 3);
  const _Float16* a0 = Acat + (size_t)(row0 + wid * 32 + srow) * DP3 + gs * 8;
  const _Float16* a1 = Acat + (size_t)(row0 + wid * 32 + 16 + srow) * DP3 + gs * 8;
  const _Float16* b0 = Bcat + (size_t)(col0 + wid * 32 + srow) * DP3 + gs * 8;
  const _Float16* b1 = Bcat + (size_t)(col0 + wid * 32 + 16 + srow) * DP3 + gs * 8;

  _Float16* const lA0 = &Ash[wid * 1024];
  _Float16* const lA1 = &Ash[wid * 1024 + 512];
  _Float16* const lB0 = &Bsh[wid * 1024];
  _Float16* const lB1 = &Bsh[wid * 1024 + 512];

  const int rl = lane & 15;
  const int q = lane >> 4;
  const int NT = DP3 >> 5;  // k-steps (18 for D=180)

#define STAGE_INTO(off)                                                        \
  do {                                                                         \
    GLOAD_LDS16(a0, lA0 + (off));                                              \
    GLOAD_LDS16(a1, lA1 + (off));                                              \
    GLOAD_LDS16(b0, lB0 + (off));                                              \
    GLOAD_LDS16(b1, lB1 + (off));                                              \
  } while (0)

#define ADVANCE() do { a0 += 32; a1 += 32; b0 += 32; b1 += 32; } while (0)

#define COMPUTE_FROM(off)                                                      \
  do {                                                                         \
    f16x8 af[4], bf[4];                                                        \
    _Pragma("unroll")                                                          \
    for (int m = 0; m < 4; ++m) {                                              \
      int ra = wr * 64 + m * 16 + rl;                                          \
      int sa = q ^ ((ra >> 1) & 3);                                            \
      af[m] = *(const f16x8*)(&Ash[(off) + ra * 32 + sa * 8]);                 \
      int rb = wc * 64 + m * 16 + rl;                                          \
      int sb = q ^ ((rb >> 1) & 3);                                            \
      bf[m] = *(const f16x8*)(&Bsh[(off) + rb * 32 + sb * 8]);                 \
    }                                                                          \
    _Pragma("unroll")                                                          \
    for (int m = 0; m < 4; ++m)                                                \
      _Pragma("unroll")                                                        \
      for (int n = 0; n < 4; ++n)                                              \
        acc[m][n] =                                                            \
            __builtin_amdgcn_mfma_f32_16x16x32_f16(af[m], bf[n], acc[m][n],    \
                                                   0, 0, 0);                   \
  } while (0)

  // prologue: stage step 0 into buf0
  STAGE_INTO(0);
  __syncthreads();

  // main 2-phase loop: stage t+1 into the other buffer, compute t, one barrier.
  for (int kt = 0; kt < NT - 2; kt += 2) {
    ADVANCE();
    STAGE_INTO(HBUF);   // stage t+1 -> buf1
    COMPUTE_FROM(0);    // compute t  <- buf0
    __syncthreads();    // drains stage loads + read-before-overwrite safety
    ADVANCE();
    STAGE_INTO(0);      // stage t+2 -> buf0
    COMPUTE_FROM(HBUF); // compute t+1 <- buf1
    __syncthreads();
  }
  ADVANCE();
  STAGE_INTO(HBUF);     // stage NT-1 -> buf1
  COMPUTE_FROM(0);      // compute NT-2
  __syncthreads();
  COMPUTE_FROM(HBUF);   // compute NT-1

#undef STAGE_INTO
#undef ADVANCE
#undef COMPUTE_FROM

  // ---- fused min/argmin epilogue ----
  // C/D frag: col = lane&15, row = (lane>>4)*4 + reg   [guide §3, m89-verified]
  float stv[4];
  #pragma unroll
  for (int n = 0; n < 4; ++n) {
    int gj = col0 + wc * 64 + n * 16 + rl;
    stv[n] = (gj < M) ? s_st[gj] : __builtin_inff();
  }
  #pragma unroll
  for (int m = 0; m < 4; ++m) {
    #pragma unroll
    for (int g = 0; g < 4; ++g) {
      int grow = row0 + wr * 64 + m * 16 + q * 4 + g;
      unsigned long long bst = ~0ull;
      #pragma unroll
      for (int n = 0; n < 4; ++n) {
        int gj = col0 + wc * 64 + n * 16 + rl;
        float val = stv[n] - acc[m][n][g];
        unsigned long long p =
            ((unsigned long long)ord_from_float(val) << 32) | (unsigned int)gj;
        if (p < bst) bst = p;
      }
      #pragma unroll
      for (int mm = 1; mm < 16; mm <<= 1) {
        unsigned long long o = shfl_xor_u64(bst, mm);
        if (o < bst) bst = o;
      }
      if (rl == 0 && grow < N) atomicMin(&packed[grow], bst);
    }
  }
}

// ---------------- finalize ----------------

__global__ __launch_bounds__(256) void finalize_kernel(
    const unsigned long long* __restrict__ packed,
    const float* __restrict__ s_in, float* __restrict__ out, int N) {
  __shared__ double sh[256];
  double s = 0.0;
  for (int i = threadIdx.x; i < N; i += 256) {
    unsigned long long p = packed[i];
    float val = float_from_ord((unsigned int)(p >> 32));
    out[1 + i] = (float)(unsigned int)(p & 0xffffffffull);
    s += (double)(s_in[i] + val);
  }
  sh[threadIdx.x] = s;
  __syncthreads();
  for (int off = 128; off > 0; off >>= 1) {
    if (threadIdx.x < off) sh[threadIdx.x] += sh[threadIdx.x + off];
    __syncthreads();
  }
  if (threadIdx.x == 0) out[0] = (float)(sh[0] / N);
}

extern "C" void kernel_launch(void* const* d_in, const int* in_sizes, int n_in,
                              void* d_out, int out_size, void* d_ws, size_t ws_size,
                              hipStream_t stream) {
  const float* inp = (const float*)d_in[0];
  const float* tgt = (const float*)d_in[1];
  float* out = (float*)d_out;

  int N = out_size - 1;  // outputs: [loss scalar, match[N]]
  int D = in_sizes[0] / N;
  int M = in_sizes[1] / D;

  int Npad = ((N + BMM - 1) / BMM) * BMM;
  int Mpad = ((M + BMM - 1) / BMM) * BMM;
  int DP = ((D + 31) / 32) * 32;
  int DP3 = 3 * DP;

  char* ws = (char*)d_ws;
  size_t off = 0;
  float* s_in = (float*)(ws + off); off += (size_t)N * 4;
  float* s_st = (float*)(ws + off); off += (size_t)M * 4;
  off = (off + 15) & ~(size_t)15;
  unsigned long long* packed = (unsigned long long*)(ws + off); off += (size_t)N * 8;
  off = (off + 15) & ~(size_t)15;
  _Float16* Acat = (_Float16*)(ws + off); off += (size_t)Npad * DP3 * 2;
  _Float16* Bcat = (_Float16*)(ws + off); off += (size_t)Mpad * DP3 * 2;

  hipMemsetAsync(packed, 0xFF, (size_t)N * sizeof(unsigned long long), stream);

  prep_A_kernel<<<Npad, 64, 0, stream>>>(inp, Acat, s_in, N, D, DP);
  prep_B_kernel<<<Mpad, 64, 0, stream>>>(tgt, Bcat, s_st, M, D, DP);

  int gx = Mpad / BMM, gy = Npad / BMM;
  mfma_pair_min_kernel<<<gx * gy, 256, 0, stream>>>(Acat, Bcat, s_st, packed,
                                                    N, M, DP3, gx);

  finalize_kernel<<<1, 256, 0, stream>>>(packed, s_in, out, N);
}

// Round 6
// 213.708 us; speedup vs baseline: 1.3320x; 1.3320x over previous
//
#include <hip/hip_runtime.h>
#include <math.h>

#define EPSF 1e-8f

typedef _Float16 f16x8 __attribute__((ext_vector_type(8)));
typedef float f32x4 __attribute__((ext_vector_type(4)));

#define GLOAD_LDS16(g, l)                                                      \
  __builtin_amdgcn_global_load_lds(                                            \
      (const __attribute__((address_space(1))) unsigned int*)(g),              \
      (__attribute__((address_space(3))) unsigned int*)(l), 16, 0, 0)

#define WAITV(n) asm volatile("s_waitcnt vmcnt(" #n ")" ::: "memory")
#define BAR() __builtin_amdgcn_s_barrier()

__device__ __forceinline__ unsigned int ord_from_float(float f) {
  unsigned int u = __float_as_uint(f);
  return (u & 0x80000000u) ? ~u : (u | 0x80000000u);
}

__device__ __forceinline__ float float_from_ord(unsigned int o) {
  return (o & 0x80000000u) ? __uint_as_float(o & 0x7fffffffu)
                           : __uint_as_float(~o);
}

__device__ __forceinline__ unsigned long long shfl_xor_u64(unsigned long long x, int m) {
  int lo = __shfl_xor((int)(unsigned int)(x & 0xffffffffull), m, 64);
  int hi = __shfl_xor((int)(unsigned int)(x >> 32), m, 64);
  return ((unsigned long long)(unsigned int)hi << 32) | (unsigned int)lo;
}

// ---------------- fused prep kernels ----------------
// Acat row (K'=3*DP): [hi(log) | hi(log) | lo(log)]; also s_in and packed-init.
__global__ __launch_bounds__(64) void prep_A_kernel(
    const float* __restrict__ inp, _Float16* __restrict__ Acat,
    float* __restrict__ s_in, unsigned long long* __restrict__ packed,
    int N, int D, int DP) {
  int r = blockIdx.x;
  const size_t base = (size_t)r * (3 * DP);
  float s = 0.f;
  for (int d = threadIdx.x; d < DP; d += 64) {
    float lg = 0.f;
    if (r < N && d < D) {
      float x = inp[(size_t)r * D + d];
      s += x;
      lg = logf(x + EPSF);
    }
    _Float16 h = (_Float16)lg;
    _Float16 l = (_Float16)(lg - (float)h);
    Acat[base + d] = h;
    Acat[base + DP + d] = h;
    Acat[base + 2 * DP + d] = l;
  }
  #pragma unroll
  for (int m = 1; m < 64; m <<= 1) s += __shfl_xor(s, m, 64);
  if (threadIdx.x == 0 && r < N) {
    s_in[r] = s;
    packed[r] = ~0ull;
  }
}

// Bcat row: [hi(tgt) | lo(tgt) | hi(tgt)]; also Stirling sums.
__global__ __launch_bounds__(64) void prep_B_kernel(
    const float* __restrict__ tgt, _Float16* __restrict__ Bcat,
    float* __restrict__ s_st, int M, int D, int DP) {
  int r = blockIdx.x;
  const size_t base = (size_t)r * (3 * DP);
  float s = 0.f;
  for (int d = threadIdx.x; d < DP; d += 64) {
    float x = 0.f;
    if (r < M && d < D) {
      x = tgt[(size_t)r * D + d];
      if (x > 1.0f)
        s += x * logf(x) - x + 0.5f * logf(6.283185307179586f * x);
    }
    _Float16 h = (_Float16)x;
    _Float16 l = (_Float16)(x - (float)h);
    Bcat[base + d] = h;
    Bcat[base + DP + d] = l;
    Bcat[base + 2 * DP + d] = h;
  }
  #pragma unroll
  for (int m = 1; m < 64; m <<= 1) s += __shfl_xor(s, m, 64);
  if (threadIdx.x == 0 && r < M) s_st[r] = s;
}

// ---------------- MFMA pair-min kernel ----------------
// 256x256 tile, 8 waves (2Mx4N), BK=32, 4 LDS buffers, prefetch depth 3,
// counted vmcnt(8) + raw s_barrier (loads stay in flight across barriers).
#define BT 256
#define BUFH 8192  // halves per buffer per operand (256 rows x 32 halves = 16 KB)

__global__ __launch_bounds__(512, 2) void mfma_pair_min_kernel(
    const _Float16* __restrict__ Acat, const _Float16* __restrict__ Bcat,
    const float* __restrict__ s_st, unsigned long long* __restrict__ packed,
    int N, int M, int KP, int gx) {
  extern __shared__ __align__(16) _Float16 smem[];
  _Float16* const AshB = smem;              // 4 * BUFH
  _Float16* const BshB = smem + 4 * BUFH;   // 4 * BUFH

  const int t = threadIdx.x;
  const int lane = t & 63;
  const int wid = t >> 6;          // 0..7
  const int wr = wid >> 2;         // 0..1  -> 128 output rows
  const int wc = wid & 3;          // 0..3  -> 64 output cols

  // XCD chunking (nwg%8==0) + column-major traversal inside each chunk:
  // the ~32 co-resident blocks of an XCD touch ~5 A-panels + ~7 B-panels -> L2-fit.
  const int nwg = gridDim.x;
  const int q8 = nwg >> 3;
  const int xcd = blockIdx.x & 7;
  const int i8 = blockIdx.x >> 3;
  int brow, bcol;
  if (q8 % gx == 0) {
    int bh = q8 / gx;              // row-bands per chunk
    brow = xcd * bh + i8 % bh;
    bcol = i8 / bh;
  } else {
    int wg = xcd * q8 + i8;
    brow = wg / gx;
    bcol = wg % gx;
  }
  const int row0 = brow * BT;
  const int col0 = bcol * BT;

  f32x4 acc[8][4] = {};

  // Staging: wave wid owns 32 rows of A and B per step (2 wave-loads of
  // 16 rows x 64B each). LDS dest linear (lane l -> row l>>2, slot l&3);
  // GLOBAL source slot pre-swizzled: LDS(r,s) = global(r, s^((r>>1)&3)).
  // (round-3/4 verified: 0 bank conflicts)
  const int srow = lane >> 2;
  const int gs = (lane & 3) ^ ((lane >> 3) & 3);
  const _Float16* const aSrc = Acat + (size_t)(row0 + wid * 32 + srow) * KP + gs * 8;
  const _Float16* const bSrc = Bcat + (size_t)(col0 + wid * 32 + srow) * KP + gs * 8;
  _Float16* const lA = AshB + wid * 1024;   // + buf*BUFH
  _Float16* const lB = BshB + wid * 1024;

#define STAGE(buf, step)                                                       \
  do {                                                                         \
    const int so_ = (step) * 32;                                               \
    GLOAD_LDS16(aSrc + so_, lA + (buf) * BUFH);                                \
    GLOAD_LDS16(aSrc + so_ + 16 * KP, lA + (buf) * BUFH + 512);                \
    GLOAD_LDS16(bSrc + so_, lB + (buf) * BUFH);                                \
    GLOAD_LDS16(bSrc + so_ + 16 * KP, lB + (buf) * BUFH + 512);                \
  } while (0)

  const int rl = lane & 15;
  const int qq = lane >> 4;
  const int sa = qq ^ ((rl >> 1) & 3);  // swizzled slot (same for all frag rows)

#define COMPUTE(buf)                                                           \
  do {                                                                         \
    const int bofs_ = (buf) * BUFH;                                            \
    f16x8 af[8], bf[4];                                                        \
    _Pragma("unroll")                                                          \
    for (int m = 0; m < 8; ++m)                                                \
      af[m] = *(const f16x8*)(&AshB[bofs_ + (wr * 128 + m * 16 + rl) * 32 + sa * 8]); \
    _Pragma("unroll")                                                          \
    for (int n = 0; n < 4; ++n)                                                \
      bf[n] = *(const f16x8*)(&BshB[bofs_ + (wc * 64 + n * 16 + rl) * 32 + sa * 8]); \
    __builtin_amdgcn_s_setprio(1);                                             \
    _Pragma("unroll")                                                          \
    for (int m = 0; m < 8; ++m)                                                \
      _Pragma("unroll")                                                        \
      for (int n = 0; n < 4; ++n)                                              \
        acc[m][n] = __builtin_amdgcn_mfma_f32_16x16x32_f16(af[m], bf[n],       \
                                                           acc[m][n], 0, 0, 0); \
    __builtin_amdgcn_s_setprio(0);                                             \
  } while (0)

  const int NT = KP >> 5;  // 18 for D=180

  // prologue: stage steps 0,1,2; wait for step 0 (8 newer loads in flight)
  STAGE(0, 0);
  STAGE(1, 1);
  STAGE(2, 2);
  WAITV(8);
  BAR();

  int kt = 0;
  for (; kt < NT - 3; ++kt) {
    STAGE((kt + 3) & 3, kt + 3);  // depth-3 prefetch
    COMPUTE(kt & 3);
    WAITV(8);                     // oldest stage (kt+1) landed; 8 stay in flight
    BAR();
  }
  COMPUTE(kt & 3);  // NT-3
  WAITV(4);
  BAR();
  ++kt;
  COMPUTE(kt & 3);  // NT-2
  WAITV(0);
  BAR();
  ++kt;
  COMPUTE(kt & 3);  // NT-1

#undef STAGE
#undef COMPUTE

  // ---- fused min/argmin epilogue ----
  // C/D frag: col = lane&15, row = (lane>>4)*4 + reg   [guide §3, m89-verified]
  float stv[4];
  #pragma unroll
  for (int n = 0; n < 4; ++n) {
    int gj = col0 + wc * 64 + n * 16 + rl;
    stv[n] = (gj < M) ? s_st[gj] : __builtin_inff();
  }
  #pragma unroll
  for (int m = 0; m < 8; ++m) {
    #pragma unroll
    for (int g = 0; g < 4; ++g) {
      int grow = row0 + wr * 128 + m * 16 + qq * 4 + g;
      unsigned long long bst = ~0ull;
      #pragma unroll
      for (int n = 0; n < 4; ++n) {
        int gj = col0 + wc * 64 + n * 16 + rl;
        float val = stv[n] - acc[m][n][g];
        unsigned long long p =
            ((unsigned long long)ord_from_float(val) << 32) | (unsigned int)gj;
        if (p < bst) bst = p;
      }
      #pragma unroll
      for (int mm = 1; mm < 16; mm <<= 1) {
        unsigned long long o = shfl_xor_u64(bst, mm);
        if (o < bst) bst = o;
      }
      if (rl == 0 && grow < N) atomicMin(&packed[grow], bst);
    }
  }
}

// ---------------- finalize ----------------

__global__ __launch_bounds__(256) void finalize_kernel(
    const unsigned long long* __restrict__ packed,
    const float* __restrict__ s_in, float* __restrict__ out, int N) {
  __shared__ double sh[256];
  double s = 0.0;
  for (int i = threadIdx.x; i < N; i += 256) {
    unsigned long long p = packed[i];
    float val = float_from_ord((unsigned int)(p >> 32));
    out[1 + i] = (float)(unsigned int)(p & 0xffffffffull);
    s += (double)(s_in[i] + val);
  }
  sh[threadIdx.x] = s;
  __syncthreads();
  for (int off = 128; off > 0; off >>= 1) {
    if (threadIdx.x < off) sh[threadIdx.x] += sh[threadIdx.x + off];
    __syncthreads();
  }
  if (threadIdx.x == 0) out[0] = (float)(sh[0] / N);
}

extern "C" void kernel_launch(void* const* d_in, const int* in_sizes, int n_in,
                              void* d_out, int out_size, void* d_ws, size_t ws_size,
                              hipStream_t stream) {
  const float* inp = (const float*)d_in[0];
  const float* tgt = (const float*)d_in[1];
  float* out = (float*)d_out;

  int N = out_size - 1;  // outputs: [loss scalar, match[N]]
  int D = in_sizes[0] / N;
  int M = in_sizes[1] / D;

  int Npad = ((N + BT - 1) / BT) * BT;
  int Mpad = ((M + BT - 1) / BT) * BT;
  int DP = ((D + 31) / 32) * 32;
  int KP = 3 * DP;  // 576 for D=180 -> 18 k-steps

  char* ws = (char*)d_ws;
  size_t off = 0;
  float* s_in = (float*)(ws + off); off += (size_t)N * 4;
  float* s_st = (float*)(ws + off); off += (size_t)M * 4;
  off = (off + 15) & ~(size_t)15;
  unsigned long long* packed = (unsigned long long*)(ws + off); off += (size_t)N * 8;
  off = (off + 15) & ~(size_t)15;
  _Float16* Acat = (_Float16*)(ws + off); off += (size_t)Npad * KP * 2;
  _Float16* Bcat = (_Float16*)(ws + off); off += (size_t)Mpad * KP * 2;

  prep_A_kernel<<<Npad, 64, 0, stream>>>(inp, Acat, s_in, packed, N, D, DP);
  prep_B_kernel<<<Mpad, 64, 0, stream>>>(tgt, Bcat, s_st, M, D, DP);

  const int ldsBytes = 8 * BUFH * 2;  // 128 KiB (4 dbuf x (A+B) x 16 KB)
  hipFuncSetAttribute((const void*)mfma_pair_min_kernel,
                      hipFuncAttributeMaxDynamicSharedMemorySize, ldsBytes);

  int gx = Mpad / BT, gy = Npad / BT;
  mfma_pair_min_kernel<<<gx * gy, 512, ldsBytes, stream>>>(Acat, Bcat, s_st,
                                                           packed, N, M, KP, gx);

  finalize_kernel<<<1, 256, 0, stream>>>(packed, s_in, out, N);
}

// Round 7
// 213.060 us; speedup vs baseline: 1.3361x; 1.0030x over previous
//
#include <hip/hip_runtime.h>
#include <math.h>

#define EPSF 1e-8f

typedef _Float16 f16x8 __attribute__((ext_vector_type(8)));
typedef float f32x4 __attribute__((ext_vector_type(4)));

#define GLOAD_LDS16(g, l)                                                      \
  __builtin_amdgcn_global_load_lds(                                            \
      (const __attribute__((address_space(1))) unsigned int*)(g),              \
      (__attribute__((address_space(3))) unsigned int*)(l), 16, 0, 0)

#define WAITV(n) asm volatile("s_waitcnt vmcnt(" #n ")" ::: "memory")
#define BAR() __builtin_amdgcn_s_barrier()

__device__ __forceinline__ unsigned int ord_from_float(float f) {
  unsigned int u = __float_as_uint(f);
  return (u & 0x80000000u) ? ~u : (u | 0x80000000u);
}

__device__ __forceinline__ float float_from_ord(unsigned int o) {
  return (o & 0x80000000u) ? __uint_as_float(o & 0x7fffffffu)
                           : __uint_as_float(~o);
}

__device__ __forceinline__ unsigned long long shfl_xor_u64(unsigned long long x, int m) {
  int lo = __shfl_xor((int)(unsigned int)(x & 0xffffffffull), m, 64);
  int hi = __shfl_xor((int)(unsigned int)(x >> 32), m, 64);
  return ((unsigned long long)(unsigned int)hi << 32) | (unsigned int)lo;
}

// ---------------- fused prep kernels ----------------
// Acat row (stride KPA): [hi(log) | hi(log) | lo(log) | 0-pad]; also s_in, packed-init.
__global__ __launch_bounds__(64) void prep_A_kernel(
    const float* __restrict__ inp, _Float16* __restrict__ Acat,
    float* __restrict__ s_in, unsigned long long* __restrict__ packed,
    int N, int D, int DP, int KPA) {
  int r = blockIdx.x;
  _Float16* row = Acat + (size_t)r * KPA;
  float s = 0.f;
  for (int d = threadIdx.x; d < DP; d += 64) {
    float lg = 0.f;
    if (r < N && d < D) {
      float x = inp[(size_t)r * D + d];
      s += x;
      lg = logf(x + EPSF);
    }
    _Float16 h = (_Float16)lg;
    _Float16 l = (_Float16)(lg - (float)h);
    row[d] = h;
    row[DP + d] = h;
    row[2 * DP + d] = l;
  }
  for (int d = threadIdx.x; d < KPA - 3 * DP; d += 64) row[3 * DP + d] = (_Float16)0.f;
  #pragma unroll
  for (int m = 1; m < 64; m <<= 1) s += __shfl_xor(s, m, 64);
  if (threadIdx.x == 0 && r < N) {
    s_in[r] = s;
    packed[r] = ~0ull;
  }
}

// Bcat row: [hi(tgt) | lo(tgt) | hi(tgt) | 0-pad]; also Stirling sums.
__global__ __launch_bounds__(64) void prep_B_kernel(
    const float* __restrict__ tgt, _Float16* __restrict__ Bcat,
    float* __restrict__ s_st, int M, int D, int DP, int KPA) {
  int r = blockIdx.x;
  _Float16* row = Bcat + (size_t)r * KPA;
  float s = 0.f;
  for (int d = threadIdx.x; d < DP; d += 64) {
    float x = 0.f;
    if (r < M && d < D) {
      x = tgt[(size_t)r * D + d];
      if (x > 1.0f)
        s += x * logf(x) - x + 0.5f * logf(6.283185307179586f * x);
    }
    _Float16 h = (_Float16)x;
    _Float16 l = (_Float16)(x - (float)h);
    row[d] = h;
    row[DP + d] = l;
    row[2 * DP + d] = h;
  }
  for (int d = threadIdx.x; d < KPA - 3 * DP; d += 64) row[3 * DP + d] = (_Float16)0.f;
  #pragma unroll
  for (int m = 1; m < 64; m <<= 1) s += __shfl_xor(s, m, 64);
  if (threadIdx.x == 0 && r < M) s_st[r] = s;
}

// ---------------- MFMA pair-min kernel: 8-phase schedule ----------------
// 256x256 tile, 8 waves (2Mx4N). LDS = 8 units of 16 KB: [buf][op][khalf],
// unit-internal layout identical to the round-3-verified swizzle (0 conflicts).
// Per phase: ds_read next quadrant | stage 1 unit | BAR | 16 MFMA | [WAITV(8)] | BAR.
#define BT 256
#define UNITH 8192  // halves per unit (256 rows x 32 halves)

__global__ __launch_bounds__(512, 2) void mfma_pair_min_kernel(
    const _Float16* __restrict__ Acat, const _Float16* __restrict__ Bcat,
    const float* __restrict__ s_st, unsigned long long* __restrict__ packed,
    int N, int M, int KPA, int gx) {
  extern __shared__ __align__(16) _Float16 smem[];  // 8 * UNITH halves = 128 KiB
  const int t = threadIdx.x;
  const int lane = t & 63;
  const int wid = t >> 6;
  const int wr = wid >> 2;  // 0..1 -> 128 output rows
  const int wc = wid & 3;   // 0..3 -> 64 output cols

  // XCD chunking + column-major traversal inside each chunk (round-6 verified)
  const int nwg = gridDim.x;
  const int q8 = nwg >> 3;
  const int xcd = blockIdx.x & 7;
  const int i8 = blockIdx.x >> 3;
  int brow, bcol;
  if (q8 % gx == 0) {
    int bh = q8 / gx;
    brow = xcd * bh + i8 % bh;
    bcol = i8 / bh;
  } else {
    int wg = xcd * q8 + i8;
    brow = wg / gx;
    bcol = wg % gx;
  }
  const int row0 = brow * BT;
  const int col0 = bcol * BT;

  // Staging: wave wid owns rows [wid*32, wid*32+32) per unit; 2 instr of
  // 16 rows x 64B. LDS dest linear; global source slot pre-swizzled:
  // LDS(r,s) = global(r, s ^ ((r>>1)&3))   (round-3/4 verified, 0 conflicts)
  const int srow = lane >> 2;
  const int gs = (lane & 3) ^ ((lane >> 3) & 3);
  const _Float16* pA0 = Acat + (size_t)(row0 + wid * 32 + srow) * KPA + gs * 8;
  const _Float16* pA1 = pA0 + (size_t)16 * KPA;
  const _Float16* pB0 = Bcat + (size_t)(col0 + wid * 32 + srow) * KPA + gs * 8;
  const _Float16* pB1 = pB0 + (size_t)16 * KPA;
  _Float16* const ldst = smem + wid * 1024;

#define STG(b_, isB_, kh_, tofs_)                                              \
  do {                                                                         \
    const _Float16* s0_ = ((isB_) ? pB0 : pA0) + (tofs_) * 64 + (kh_) * 32;    \
    const _Float16* s1_ = ((isB_) ? pB1 : pA1) + (tofs_) * 64 + (kh_) * 32;    \
    _Float16* d_ = ldst + ((((b_) << 2) | ((isB_) << 1) | (kh_)) * UNITH);     \
    GLOAD_LDS16(s0_, d_);                                                      \
    GLOAD_LDS16(s1_, d_ + 512);                                                \
  } while (0)

  const int rl = lane & 15;
  const int q = lane >> 4;
  const int sa = q ^ ((rl >> 1) & 3);

#define LDA4(dst_, b_, kh_, mh_)                                               \
  do {                                                                         \
    const _Float16* p_ = smem + ((((b_) << 2) | (kh_)) * UNITH);               \
    _Pragma("unroll") for (int mm_ = 0; mm_ < 4; ++mm_)                        \
        dst_[mm_] = *(const f16x8*)(p_ + (wr * 128 + (mh_) * 64 + mm_ * 16 + rl) * 32 + sa * 8); \
  } while (0)

#define LDB4(dst_, b_, kh_)                                                    \
  do {                                                                         \
    const _Float16* p_ = smem + ((((b_) << 2) | 2 | (kh_)) * UNITH);           \
    _Pragma("unroll") for (int nn_ = 0; nn_ < 4; ++nn_)                        \
        dst_[nn_] = *(const f16x8*)(p_ + (wc * 64 + nn_ * 16 + rl) * 32 + sa * 8); \
  } while (0)

  f32x4 acc[8][4] = {};
  f16x8 afA[4], afB[4], bfA[4], bfB[4];

#define MMQ(af_, bf_, mh_)                                                     \
  do {                                                                         \
    __builtin_amdgcn_s_setprio(1);                                             \
    _Pragma("unroll") for (int mm_ = 0; mm_ < 4; ++mm_)                        \
        _Pragma("unroll") for (int nn_ = 0; nn_ < 4; ++nn_)                    \
            acc[(mh_) * 4 + mm_][nn_] = __builtin_amdgcn_mfma_f32_16x16x32_f16(\
                af_[mm_], bf_[nn_], acc[(mh_) * 4 + mm_][nn_], 0, 0, 0);       \
    __builtin_amdgcn_s_setprio(0);                                             \
  } while (0)

  // ---- prologue: stage T0 fully + T1 (A-k0, B-k0, B-k1); T1.A-k1 at ph0 ----
  STG(0, 0, 0, 0); STG(0, 1, 0, 0); STG(0, 0, 1, 0); STG(0, 1, 1, 0);
  STG(1, 0, 0, 1); STG(1, 1, 0, 1); STG(1, 1, 1, 1);
  WAITV(10);
  BAR();
  LDA4(afA, 0, 0, 0);
  LDB4(bfA, 0, 0);

  // TT = KPA/64 real K-tiles (odd); LITERS = (TT-3)/2 steady iters,
  // then 1 reduced-staging iter, then a 1-tile epilogue.
  const int LITERS = ((KPA >> 6) - 3) >> 1;
  for (int i = 0; i < LITERS; ++i) {
    LDA4(afB, 0, 0, 1); STG(1, 0, 1, 1);                  BAR(); MMQ(afA, bfA, 0); WAITV(8); BAR();
    LDA4(afA, 0, 1, 0); LDB4(bfB, 0, 1); STG(0, 0, 0, 2); BAR(); MMQ(afB, bfA, 1);           BAR();
    LDA4(afB, 0, 1, 1); STG(0, 1, 0, 2);                  BAR(); MMQ(afA, bfB, 0); WAITV(8); BAR();
    LDA4(afA, 1, 0, 0); LDB4(bfA, 1, 0); STG(0, 1, 1, 2); BAR(); MMQ(afB, bfB, 1);           BAR();
    LDA4(afB, 1, 0, 1); STG(0, 0, 1, 2);                  BAR(); MMQ(afA, bfA, 0); WAITV(8); BAR();
    LDA4(afA, 1, 1, 0); LDB4(bfB, 1, 1); STG(1, 1, 0, 3); BAR(); MMQ(afB, bfA, 1);           BAR();
    LDA4(afB, 1, 1, 1); STG(1, 0, 0, 3);                  BAR(); MMQ(afA, bfB, 0); WAITV(8); BAR();
    LDA4(afA, 0, 0, 0); LDB4(bfA, 0, 0); STG(1, 1, 1, 3); BAR(); MMQ(afB, bfB, 1);           BAR();
    pA0 += 128; pA1 += 128; pB0 += 128; pB1 += 128;
  }

  // reduced-staging iter: stages own T1.A-k1 + next tile (b0 units) only
  LDA4(afB, 0, 0, 1); STG(1, 0, 1, 1);                  BAR(); MMQ(afA, bfA, 0); WAITV(8); BAR();
  LDA4(afA, 0, 1, 0); LDB4(bfB, 0, 1); STG(0, 0, 0, 2); BAR(); MMQ(afB, bfA, 1);           BAR();
  LDA4(afB, 0, 1, 1); STG(0, 1, 0, 2);                  BAR(); MMQ(afA, bfB, 0); WAITV(8); BAR();
  LDA4(afA, 1, 0, 0); LDB4(bfA, 1, 0); STG(0, 1, 1, 2); BAR(); MMQ(afB, bfB, 1);           BAR();
  LDA4(afB, 1, 0, 1); STG(0, 0, 1, 2);                  BAR(); MMQ(afA, bfA, 0); WAITV(8); BAR();
  LDA4(afA, 1, 1, 0); LDB4(bfB, 1, 1);                  BAR(); MMQ(afB, bfA, 1);           BAR();
  LDA4(afB, 1, 1, 1);                                   BAR(); MMQ(afA, bfB, 0); WAITV(4); BAR();
  LDA4(afA, 0, 0, 0); LDB4(bfA, 0, 0);                  BAR(); MMQ(afB, bfB, 1);           BAR();

  // epilogue: last real tile (b0), 4 phases, drain
  LDA4(afB, 0, 0, 1);                                   BAR(); MMQ(afA, bfA, 0); WAITV(0); BAR();
  LDA4(afA, 0, 1, 0); LDB4(bfB, 0, 1);                  BAR(); MMQ(afB, bfA, 1);           BAR();
  LDA4(afB, 0, 1, 1);                                   BAR(); MMQ(afA, bfB, 0);           BAR();
                                                        BAR(); MMQ(afB, bfB, 1);

#undef STG
#undef LDA4
#undef LDB4
#undef MMQ

  // ---- fused min/argmin epilogue ----
  // C/D frag: col = lane&15, row = (lane>>4)*4 + reg   [guide §3, m89-verified]
  float stv[4];
  #pragma unroll
  for (int n = 0; n < 4; ++n) {
    int gj = col0 + wc * 64 + n * 16 + rl;
    stv[n] = (gj < M) ? s_st[gj] : __builtin_inff();
  }
  #pragma unroll
  for (int m = 0; m < 8; ++m) {
    #pragma unroll
    for (int g = 0; g < 4; ++g) {
      int grow = row0 + wr * 128 + m * 16 + q * 4 + g;
      unsigned long long bst = ~0ull;
      #pragma unroll
      for (int n = 0; n < 4; ++n) {
        int gj = col0 + wc * 64 + n * 16 + rl;
        float val = stv[n] - acc[m][n][g];
        unsigned long long p =
            ((unsigned long long)ord_from_float(val) << 32) | (unsigned int)gj;
        if (p < bst) bst = p;
      }
      #pragma unroll
      for (int mm = 1; mm < 16; mm <<= 1) {
        unsigned long long o = shfl_xor_u64(bst, mm);
        if (o < bst) bst = o;
      }
      if (rl == 0 && grow < N) atomicMin(&packed[grow], bst);
    }
  }
}

// ---------------- finalize ----------------

__global__ __launch_bounds__(256) void finalize_kernel(
    const unsigned long long* __restrict__ packed,
    const float* __restrict__ s_in, float* __restrict__ out, int N) {
  __shared__ double sh[256];
  double s = 0.0;
  for (int i = threadIdx.x; i < N; i += 256) {
    unsigned long long p = packed[i];
    float val = float_from_ord((unsigned int)(p >> 32));
    out[1 + i] = (float)(unsigned int)(p & 0xffffffffull);
    s += (double)(s_in[i] + val);
  }
  sh[threadIdx.x] = s;
  __syncthreads();
  for (int off = 128; off > 0; off >>= 1) {
    if (threadIdx.x < off) sh[threadIdx.x] += sh[threadIdx.x + off];
    __syncthreads();
  }
  if (threadIdx.x == 0) out[0] = (float)(sh[0] / N);
}

extern "C" void kernel_launch(void* const* d_in, const int* in_sizes, int n_in,
                              void* d_out, int out_size, void* d_ws, size_t ws_size,
                              hipStream_t stream) {
  const float* inp = (const float*)d_in[0];
  const float* tgt = (const float*)d_in[1];
  float* out = (float*)d_out;

  int N = out_size - 1;  // outputs: [loss scalar, match[N]]
  int D = in_sizes[0] / N;
  int M = in_sizes[1] / D;

  int Npad = ((N + BT - 1) / BT) * BT;
  int Mpad = ((M + BT - 1) / BT) * BT;
  int DP = ((D + 31) / 32) * 32;
  int TT = (3 * DP + 63) / 64;    // K-tiles of 64
  if ((TT & 1) == 0) ++TT;        // structure needs odd tile count
  int KPA = TT * 64;              // 576 for D=180 (9 tiles, no pad)

  char* ws = (char*)d_ws;
  size_t off = 0;
  float* s_in = (float*)(ws + off); off += (size_t)N * 4;
  float* s_st = (float*)(ws + off); off += (size_t)M * 4;
  off = (off + 15) & ~(size_t)15;
  unsigned long long* packed = (unsigned long long*)(ws + off); off += (size_t)N * 8;
  off = (off + 15) & ~(size_t)15;
  _Float16* Acat = (_Float16*)(ws + off); off += (size_t)Npad * KPA * 2;
  _Float16* Bcat = (_Float16*)(ws + off); off += (size_t)Mpad * KPA * 2;

  prep_A_kernel<<<Npad, 64, 0, stream>>>(inp, Acat, s_in, packed, N, D, DP, KPA);
  prep_B_kernel<<<Mpad, 64, 0, stream>>>(tgt, Bcat, s_st, M, D, DP, KPA);

  const int ldsBytes = 8 * UNITH * 2;  // 128 KiB
  hipFuncSetAttribute((const void*)mfma_pair_min_kernel,
                      hipFuncAttributeMaxDynamicSharedMemorySize, ldsBytes);

  int gx = Mpad / BT, gy = Npad / BT;
  mfma_pair_min_kernel<<<gx * gy, 512, ldsBytes, stream>>>(Acat, Bcat, s_st,
                                                           packed, N, M, KPA, gx);

  finalize_kernel<<<1, 256, 0, stream>>>(packed, s_in, out, N);
}